// Round 13
// baseline (272.996 us; speedup 1.0000x reference)
//
#include <hip/hip_runtime.h>
#include <math.h>

#define N_NODES 50000
#define N_EDGES 800000
#define N_GRAPHS 64
#define NEG_SLOPE 0.2f
#define N_REP 64                            // pooled-sum replicas
#define NBKT ((N_NODES + 127) >> 7)         // 391 coarse buckets (128 nodes each)
#define BIN_BLOCKS 64
#define EPB ((N_EDGES + BIN_BLOCKS - 1) / BIN_BLOCKS)  // 12500 edges/block
#define QCAP 16                             // LDS queue entries per bucket
#define EBCAP 4352                          // per-bucket staging cap in k_csr

typedef __attribute__((ext_vector_type(8))) short short8;
typedef __attribute__((ext_vector_type(4))) float f32x4;

__device__ __forceinline__ float lrelu(float x) { return x > 0.f ? x : NEG_SLOPE * x; }

__device__ __forceinline__ unsigned short f2bf(float f) {
    union { float f; unsigned int u; } v; v.f = f;
    unsigned int r = (v.u + 0x7fffu + ((v.u >> 16) & 1u)) >> 16;  // RNE
    return (unsigned short)r;
}
__device__ __forceinline__ float bf2f(unsigned short b) {
    union { unsigned int u; float f; } v; v.u = ((unsigned int)b) << 16;
    return v.f;
}

__device__ __forceinline__ int lower_bound_i(const int* __restrict__ a, int n, int v) {
    int lo = 0, hi = n;
    while (lo < hi) { int m = (lo + hi) >> 1; if (a[m] < v) lo = m + 1; else hi = m; }
    return lo;
}

// ============ CSR build: 2-level LDS-staged binning sort ============

// Phase A: per-block bucket histogram (no global atomics) + zero `sums`.
__global__ __launch_bounds__(256) void k_hist(const int* __restrict__ dst,
                                              int* __restrict__ part,
                                              float4* __restrict__ sums4) {
    __shared__ int h[NBKT];
    const int t = threadIdx.x;
    for (int i = t; i < NBKT; i += 256) h[i] = 0;
    for (int i = blockIdx.x * 256 + t; i < N_REP * N_GRAPHS * 16; i += BIN_BLOCKS * 256)
        sums4[i] = make_float4(0.f, 0.f, 0.f, 0.f);
    __syncthreads();
    for (int e = blockIdx.x * 256 + t; e < N_EDGES; e += BIN_BLOCKS * 256)
        atomicAdd(&h[dst[e] >> 7], 1);
    __syncthreads();
    for (int i = t; i < NBKT; i += 256) part[blockIdx.x * NBKT + i] = h[i];
}

// Phase B: sum partials, wave-scan 8-aligned bucket starts, zero cursors.
__global__ __launch_bounds__(512) void k_bscan(const int* __restrict__ part,
                                               int* __restrict__ bkt_cnt,
                                               int* __restrict__ bkt_start8,
                                               int* __restrict__ bkt_cursor) {
    __shared__ int tot[NBKT];
    const int t = threadIdx.x;
    for (int b = t; b < NBKT; b += 512) {
        int s = 0;
        for (int k = 0; k < BIN_BLOCKS; ++k) s += part[k * NBKT + b];
        tot[b] = s;
        bkt_cnt[b] = s;
    }
    __syncthreads();
    if (t < 64) {
        int carry = 0;
        for (int c = 0; c < (NBKT + 63) / 64; ++c) {
            int b = c * 64 + t;
            int v = (b < NBKT) ? ((tot[b] + 7) & ~7) : 0;
            int x = v;
#pragma unroll
            for (int off = 1; off < 64; off <<= 1) {
                int y = __shfl_up(x, off, 64);
                if (t >= off) x += y;
            }
            if (b < NBKT) { bkt_start8[b] = carry + x - v; bkt_cursor[b] = 0; }
            carry += __shfl(x, 63, 64);
        }
    }
}

// Phase C: bin edges into bucket regions with LDS-staged 64B-aligned flushes.
__global__ __launch_bounds__(256) void k_bin(const int* __restrict__ src,
                                             const int* __restrict__ dst,
                                             const int* __restrict__ bkt_start8,
                                             int* __restrict__ bkt_cursor,
                                             uint2* __restrict__ binbuf) {
    __shared__ uint2 q[NBKT][QCAP];   // ~50 KB
    __shared__ int qc[NBKT];
    const int t = threadIdx.x;
    for (int i = t; i < NBKT; i += 256) qc[i] = 0;
    __syncthreads();
    const int beg = blockIdx.x * EPB;
    const int end = min(beg + EPB, N_EDGES);
    for (int rb = beg; rb < end; rb += 256) {
        const int e = rb + t;
        if (e < end) {
            int s = src[e], d = dst[e];
            int b = d >> 7;
            int p = atomicAdd(&qc[b], 1);
            if (p < QCAP) {
                q[b][p] = make_uint2((unsigned)s, (unsigned)d);
            } else {   // overflow: correct (rare) direct scattered write
                int g = atomicAdd(&bkt_cursor[b], 1);
                binbuf[bkt_start8[b] + g] = make_uint2((unsigned)s, (unsigned)d);
            }
        }
        __syncthreads();
        for (int b = t; b < NBKT; b += 256) {
            int c = qc[b]; if (c > QCAP) c = QCAP;
            int n = c & ~7;                    // flush whole 64B lines
            if (n) {
                int g = atomicAdd(&bkt_cursor[b], n);
                uint2* o = binbuf + bkt_start8[b] + g;
                for (int k = 0; k < n; ++k) o[k] = q[b][k];
                for (int k = 0; k < c - n; ++k) q[b][k] = q[b][n + k];
            }
            qc[b] = c - n;
        }
        __syncthreads();
    }
    for (int b = t; b < NBKT; b += 256) {      // drain remainder (<8/bucket)
        int c = qc[b];
        if (c) {
            int g = atomicAdd(&bkt_cursor[b], c);
            uint2* o = binbuf + bkt_start8[b] + g;
            for (int k = 0; k < c; ++k) o[k] = q[b][k];
        }
    }
}

// Phase D: per-bucket fine CSR in LDS; write csr_src + rbeg/rend.
__global__ __launch_bounds__(256) void k_csr(const uint2* __restrict__ binbuf,
                                             const int* __restrict__ bkt_cnt,
                                             const int* __restrict__ bkt_start8,
                                             int* __restrict__ csr_src,
                                             int* __restrict__ rbeg,
                                             int* __restrict__ rend) {
    __shared__ uint2 eb[EBCAP];   // ~34.8 KB
    __shared__ int fc[128], pfx[128], cur[128];
    const int b = blockIdx.x, t = threadIdx.x;
    const int d0 = b << 7;
    const int nd = min(128, N_NODES - d0);
    const int cnt = bkt_cnt[b];
    const int base = bkt_start8[b];
    for (int i = t; i < 128; i += 256) fc[i] = 0;
    const bool staged = (cnt <= EBCAP);
    if (staged) for (int i = t; i < cnt; i += 256) eb[i] = binbuf[base + i];
    __syncthreads();
    if (staged) { for (int i = t; i < cnt; i += 256) atomicAdd(&fc[eb[i].y - d0], 1); }
    else        { for (int i = t; i < cnt; i += 256) atomicAdd(&fc[binbuf[base + i].y - d0], 1); }
    __syncthreads();
    if (t == 0) { int run = 0; for (int i = 0; i < 128; ++i) { pfx[i] = run; run += fc[i]; } }
    __syncthreads();
    if (t < nd) { rbeg[d0 + t] = base + pfx[t]; rend[d0 + t] = base + pfx[t] + fc[t]; }
    for (int i = t; i < 128; i += 256) cur[i] = pfx[i];
    __syncthreads();
    if (staged) {
        for (int i = t; i < cnt; i += 256) {
            int p = atomicAdd(&cur[eb[i].y - d0], 1);
            csr_src[base + p] = (int)eb[i].x;
        }
    } else {
        for (int i = t; i < cnt; i += 256) {
            uint2 e = binbuf[base + i];
            int p = atomicAdd(&cur[e.y - d0], 1);
            csr_src[base + p] = (int)e.x;
        }
    }
}

// ---------------- Layer 1 logits: a_s/a_d per node ----------------
__global__ __launch_bounds__(256) void k_gemm1(const float* __restrict__ x,
                                               const float* __restrict__ W1,
                                               const float* __restrict__ att_s,
                                               const float* __restrict__ att_d,
                                               float4* __restrict__ a_s,
                                               float4* __restrict__ a_d) {
    __shared__ float Ws[5 * 256];
    const int t = threadIdx.x;
    for (int i = t; i < 5 * 256; i += 256) Ws[i] = W1[i];
    __syncthreads();
    const int wave = t >> 6, lane = t & 63;
    const int n = blockIdx.x * 4 + wave;
    if (n >= N_NODES) return;
    float x0 = x[n * 5 + 0], x1 = x[n * 5 + 1], x2 = x[n * 5 + 2],
          x3 = x[n * 5 + 3], x4 = x[n * 5 + 4];
    float vs[4], vd[4];
#pragma unroll
    for (int hd = 0; hd < 4; ++hd) {
        const int c = hd * 64 + lane;
        float h = x0 * Ws[c] + x1 * Ws[256 + c] + x2 * Ws[512 + c] +
                  x3 * Ws[768 + c] + x4 * Ws[1024 + c];
        vs[hd] = h * att_s[c];
        vd[hd] = h * att_d[c];
    }
#pragma unroll
    for (int off = 32; off; off >>= 1) {
#pragma unroll
        for (int hd = 0; hd < 4; ++hd) {
            vs[hd] += __shfl_xor(vs[hd], off, 64);
            vd[hd] += __shfl_xor(vd[hd], off, 64);
        }
    }
    if (lane == 0) {
        a_s[n] = make_float4(vs[0], vs[1], vs[2], vs[3]);
        a_d[n] = make_float4(vd[0], vd[1], vd[2], vd[3]);
    }
}

// ---------------- Layer 1 aggregation: SUM-SWAPPED ----------------
__global__ __launch_bounds__(256) void k_agg1(const float* __restrict__ x,
                                              const float* __restrict__ W1,
                                              const float4* __restrict__ asv,
                                              const float4* __restrict__ adv,
                                              const int* __restrict__ rbeg,
                                              const int* __restrict__ rend,
                                              const int* __restrict__ csr_src,
                                              const float* __restrict__ b1,
                                              unsigned short* __restrict__ out1rm) {
    __shared__ float hand[4][4][24];
    const int t = threadIdx.x;
    const int wave = t >> 6, lane = t & 63;
    const int grp = lane >> 4, l16 = lane & 15;
    const int d = blockIdx.x * 16 + wave * 4 + grp;

    float w1r[4][5], bias[4];
#pragma unroll
    for (int h = 0; h < 4; ++h) {
#pragma unroll
        for (int i = 0; i < 5; ++i) w1r[h][i] = W1[i * 256 + h * 64 + lane];
        bias[h] = b1[h * 64 + lane];
    }

    const int beg = rbeg[d], end = rend[d];
    const float4 ad = adv[d];

    float den[4] = {0.f, 0.f, 0.f, 0.f};
    float xw[4][5];
#pragma unroll
    for (int h = 0; h < 4; ++h)
#pragma unroll
        for (int i = 0; i < 5; ++i) xw[h][i] = 0.f;

    for (int cb = beg; cb < end; cb += 16) {
        const int j = cb + l16;
        if (j < end) {
            const int s = csr_src[j];
            const float4 a = asv[s];
            float w[4];
            w[0] = __expf(lrelu(a.x + ad.x));
            w[1] = __expf(lrelu(a.y + ad.y));
            w[2] = __expf(lrelu(a.z + ad.z));
            w[3] = __expf(lrelu(a.w + ad.w));
            const float* xp = x + (size_t)s * 5;
            float xv[5];
#pragma unroll
            for (int i = 0; i < 5; ++i) xv[i] = xp[i];
#pragma unroll
            for (int h = 0; h < 4; ++h) {
                den[h] += w[h];
#pragma unroll
                for (int i = 0; i < 5; ++i) xw[h][i] += w[h] * xv[i];
            }
        }
    }

#pragma unroll
    for (int off = 1; off < 16; off <<= 1) {
#pragma unroll
        for (int h = 0; h < 4; ++h) {
            den[h] += __shfl_xor(den[h], off, 64);
#pragma unroll
            for (int i = 0; i < 5; ++i) xw[h][i] += __shfl_xor(xw[h][i], off, 64);
        }
    }

    {   // self loop
        const float4 as = asv[d];
        float w[4];
        w[0] = __expf(lrelu(as.x + ad.x));
        w[1] = __expf(lrelu(as.y + ad.y));
        w[2] = __expf(lrelu(as.z + ad.z));
        w[3] = __expf(lrelu(as.w + ad.w));
        const float* xp = x + (size_t)d * 5;
        float xv[5];
#pragma unroll
        for (int i = 0; i < 5; ++i) xv[i] = xp[i];
#pragma unroll
        for (int h = 0; h < 4; ++h) {
            den[h] += w[h];
#pragma unroll
            for (int i = 0; i < 5; ++i) xw[h][i] += w[h] * xv[i];
        }
    }

    if (l16 == 0) {
#pragma unroll
        for (int h = 0; h < 4; ++h) hand[wave][grp][h] = den[h];
#pragma unroll
        for (int h = 0; h < 4; ++h)
#pragma unroll
            for (int i = 0; i < 5; ++i) hand[wave][grp][4 + h * 5 + i] = xw[h][i];
    }
    __syncthreads();

#pragma unroll
    for (int n = 0; n < 4; ++n) {
        const int dn = blockIdx.x * 16 + wave * 4 + n;
        unsigned short* op = out1rm + (size_t)dn * 256;
#pragma unroll
        for (int h = 0; h < 4; ++h) {
            const float dh = hand[wave][n][h] + 1e-16f;
            float hh = hand[wave][n][4 + h * 5 + 0] * w1r[h][0]
                     + hand[wave][n][4 + h * 5 + 1] * w1r[h][1]
                     + hand[wave][n][4 + h * 5 + 2] * w1r[h][2]
                     + hand[wave][n][4 + h * 5 + 3] * w1r[h][3]
                     + hand[wave][n][4 + h * 5 + 4] * w1r[h][4];
            op[h * 64 + lane] = f2bf(fmaxf(hh / dh + bias[h], 0.f));
        }
    }
}

// ---------------- Layer 2: MFMA GEMM + attention logits ----------------
__global__ __launch_bounds__(256) void k_gemm2(const unsigned short* __restrict__ in,
                                               const float* __restrict__ W2,
                                               const float* __restrict__ att_s2,
                                               const float* __restrict__ att_d2,
                                               unsigned short* __restrict__ h2b,
                                               float* __restrict__ a_s2,
                                               float* __restrict__ a_d2) {
    __shared__ unsigned short lW[16384];  // 32 KB
    const int t = threadIdx.x;
    for (int idx = t; idx < 16384; idx += 256) {
        int j = idx & 7, c16 = (idx >> 3) & 15, tt = (idx >> 7) & 3,
            g = (idx >> 9) & 3, s = idx >> 11;
        int k = 32 * s + 8 * g + j, c = 16 * tt + c16;
        lW[idx] = f2bf(W2[k * 64 + c]);
    }
    __syncthreads();
    const int wave = t >> 6, lane = t & 63;
    const int g = lane >> 4, c16 = lane & 15;
    const int nb = blockIdx.x * 64 + wave * 16;
    if (nb >= N_NODES) return;

    f32x4 acc[4];
#pragma unroll
    for (int i = 0; i < 4; ++i) acc[i] = (f32x4){0.f, 0.f, 0.f, 0.f};

    const unsigned short* arow = in + (size_t)(nb + c16) * 256;
#pragma unroll
    for (int s = 0; s < 8; ++s) {
        short8 a = *reinterpret_cast<const short8*>(arow + 32 * s + 8 * g);
#pragma unroll
        for (int tt = 0; tt < 4; ++tt) {
            short8 b = *reinterpret_cast<const short8*>(
                lW + ((((s * 4 + g) * 4 + tt) * 16 + c16) << 3));
            acc[tt] = __builtin_amdgcn_mfma_f32_16x16x32_bf16(a, b, acc[tt], 0, 0, 0);
        }
    }

    float attS[4], attD[4];
#pragma unroll
    for (int tt = 0; tt < 4; ++tt) {
        attS[tt] = att_s2[16 * tt + c16];
        attD[tt] = att_d2[16 * tt + c16];
    }
#pragma unroll
    for (int r = 0; r < 4; ++r) {
        const int node = nb + g * 4 + r;
        const bool ok = node < N_NODES;
        float vs = 0.f, vd = 0.f;
#pragma unroll
        for (int tt = 0; tt < 4; ++tt) {
            float v = acc[tt][r];
            if (ok) h2b[(size_t)node * 64 + 16 * tt + c16] = f2bf(v);
            vs += v * attS[tt];
            vd += v * attD[tt];
        }
#pragma unroll
        for (int off = 1; off < 16; off <<= 1) {
            vs += __shfl_xor(vs, off, 64);
            vd += __shfl_xor(vd, off, 64);
        }
        if (ok && c16 == 0) { a_s2[node] = vs; a_d2[node] = vd; }
    }
}

// ---------------- Layer 2 aggregation + fused pool (replicated accumulators) --
__global__ __launch_bounds__(256) void k_agg2(const unsigned short* __restrict__ h2b,
                                              const float* __restrict__ as_,
                                              const float* __restrict__ ad_,
                                              const int* __restrict__ rbeg,
                                              const int* __restrict__ rend,
                                              const int* __restrict__ csr_src,
                                              const float* __restrict__ b2,
                                              const int* __restrict__ batch,
                                              float* __restrict__ sums) {
    const int wave = threadIdx.x >> 6, lane = threadIdx.x & 63;
    const int d = blockIdx.x * 4 + wave;
    if (d >= N_NODES) return;
    const int beg = rbeg[d], end = rend[d];
    const float adl = ad_[d];

    float den, acc;
    {
        float w = __expf(lrelu(as_[d] + adl));
        den = (lane == 0) ? w : 0.f;
        acc = w * bf2f(h2b[(size_t)d * 64 + lane]);
    }
    for (int c = beg; c < end; c += 64) {
        int rem = end - c; if (rem > 64) rem = 64;
        int sreg = 0;
        float wr = 0.f;
        if (lane < rem) {
            sreg = csr_src[c + lane];
            wr = __expf(lrelu(as_[sreg] + adl));
            den += wr;
        }
        int e = 0;
        for (; e + 8 <= rem; e += 8) {
            int sq[8];
#pragma unroll
            for (int q = 0; q < 8; ++q) sq[q] = __shfl(sreg, e + q, 64);
            unsigned short vq[8];
#pragma unroll
            for (int q = 0; q < 8; ++q) vq[q] = h2b[(size_t)sq[q] * 64 + lane];
#pragma unroll
            for (int q = 0; q < 8; ++q) {
                acc += __shfl(wr, e + q, 64) * bf2f(vq[q]);
            }
        }
        for (; e < rem; ++e) {
            int s = __shfl(sreg, e, 64);
            acc += __shfl(wr, e, 64) * bf2f(h2b[(size_t)s * 64 + lane]);
        }
    }
#pragma unroll
    for (int off = 32; off; off >>= 1) den += __shfl_xor(den, off, 64);
    float val = fmaxf(acc / (den + 1e-16f) + b2[lane], 0.f);
    const int rep = blockIdx.x & (N_REP - 1);
    atomicAdd(&sums[(size_t)rep * (N_GRAPHS * 64) + batch[d] * 64 + lane], val);
}

// ---------------- Final: reduce replicas + mean + 64->2 linear ----------------
__global__ __launch_bounds__(64) void k_final(const float* __restrict__ sums,
                                              const int* __restrict__ batch,
                                              const float* __restrict__ linW,
                                              const float* __restrict__ linb,
                                              float* __restrict__ out) {
    const int g = blockIdx.x;
    const int lane = threadIdx.x;
    float s = 0.f;
#pragma unroll 8
    for (int r = 0; r < N_REP; ++r)
        s += sums[(size_t)r * (N_GRAPHS * 64) + g * 64 + lane];
    int beg = lower_bound_i(batch, N_NODES, g);
    int end = lower_bound_i(batch, N_NODES, g + 1);
    float val = s / fmaxf((float)(end - beg), 1.0f);
    float v0 = val * linW[lane * 2 + 0];
    float v1 = val * linW[lane * 2 + 1];
#pragma unroll
    for (int off = 32; off; off >>= 1) {
        v0 += __shfl_xor(v0, off, 64);
        v1 += __shfl_xor(v1, off, 64);
    }
    if (lane == 0) {
        out[g * 2 + 0] = v0 + linb[0];
        out[g * 2 + 1] = v1 + linb[1];
    }
}

extern "C" void kernel_launch(void* const* d_in, const int* in_sizes, int n_in,
                              void* d_out, int out_size, void* d_ws, size_t ws_size,
                              hipStream_t stream) {
    const float* x    = (const float*)d_in[0];
    const int*   ei   = (const int*)d_in[1];
    const int*   bat  = (const int*)d_in[2];
    const float* W1   = (const float*)d_in[3];
    const float* as1  = (const float*)d_in[4];
    const float* ad1  = (const float*)d_in[5];
    const float* b1   = (const float*)d_in[6];
    const float* W2   = (const float*)d_in[7];
    const float* as2  = (const float*)d_in[8];
    const float* ad2  = (const float*)d_in[9];
    const float* b2   = (const float*)d_in[10];
    const float* linW = (const float*)d_in[11];
    const float* linb = (const float*)d_in[12];
    float* out = (float*)d_out;

    const int* src = ei;
    const int* dst = ei + N_EDGES;

    char* w = (char*)d_ws;
#define ALLOC(ptr_t, name, bytes) \
    ptr_t name = (ptr_t)w; w += ((size_t)(bytes) + 255) & ~(size_t)255;

    ALLOC(unsigned short*, out1rm, (size_t)N_NODES * 256 * 2)
    ALLOC(float4*, a_s1, (size_t)N_NODES * 16)
    ALLOC(float4*, a_d1, (size_t)N_NODES * 16)
    ALLOC(unsigned short*, h2b, (size_t)N_NODES * 64 * 2)
    ALLOC(float*, a_s2, (size_t)N_NODES * 4)
    ALLOC(float*, a_d2, (size_t)N_NODES * 4)
    ALLOC(float*, sums, (size_t)N_REP * N_GRAPHS * 64 * 4)
    ALLOC(int*, part, (size_t)BIN_BLOCKS * NBKT * 4)
    ALLOC(int*, bkt_cnt, (size_t)NBKT * 4)
    ALLOC(int*, bkt_start8, (size_t)NBKT * 4)
    ALLOC(int*, bkt_cursor, (size_t)NBKT * 4)
    ALLOC(uint2*, binbuf, ((size_t)N_EDGES + NBKT * 8) * 8)
    ALLOC(int*, csr_src, ((size_t)N_EDGES + NBKT * 8) * 4)
    ALLOC(int*, rbeg, (size_t)N_NODES * 4)
    ALLOC(int*, rend, (size_t)N_NODES * 4)
#undef ALLOC

    // CSR build: binning sort (no memsets needed)
    k_hist<<<BIN_BLOCKS, 256, 0, stream>>>(dst, part, (float4*)sums);
    k_bscan<<<1, 512, 0, stream>>>(part, bkt_cnt, bkt_start8, bkt_cursor);
    k_bin<<<BIN_BLOCKS, 256, 0, stream>>>(src, dst, bkt_start8, bkt_cursor, binbuf);
    k_csr<<<NBKT, 256, 0, stream>>>(binbuf, bkt_cnt, bkt_start8, csr_src, rbeg, rend);

    // Layer 1
    k_gemm1<<<(N_NODES + 3) / 4, 256, 0, stream>>>(x, W1, as1, ad1, a_s1, a_d1);
    k_agg1<<<N_NODES / 16, 256, 0, stream>>>(x, W1, a_s1, a_d1, rbeg, rend, csr_src, b1, out1rm);
    // Layer 2 (MFMA)
    k_gemm2<<<(N_NODES + 63) / 64, 256, 0, stream>>>(out1rm, W2, as2, ad2, h2b, a_s2, a_d2);
    k_agg2<<<(N_NODES + 3) / 4, 256, 0, stream>>>(h2b, a_s2, a_d2, rbeg, rend, csr_src, b2,
                                                  bat, sums);
    // Reduce replicas + mean + linear
    k_final<<<N_GRAPHS, 64, 0, stream>>>(sums, bat, linW, linb, out);
}

// Round 14
// 215.333 us; speedup vs baseline: 1.2678x; 1.2678x over previous
//
#include <hip/hip_runtime.h>
#include <math.h>

#define N_NODES 50000
#define N_EDGES 800000
#define N_GRAPHS 64
#define NEG_SLOPE 0.2f
#define SCAN_BS 512
#define SCAN_NB ((N_NODES + SCAN_BS - 1) / SCAN_BS)   // 98
#define N_REP 64   // pooled-sum replicas (contention breaker)
#define ZERO_INT4 ((N_NODES * 4 + N_REP * N_GRAPHS * 64 * 4) / 16)

typedef __attribute__((ext_vector_type(8))) short short8;
typedef __attribute__((ext_vector_type(4))) float f32x4;

__device__ __forceinline__ float lrelu(float x) { return x > 0.f ? x : NEG_SLOPE * x; }

__device__ __forceinline__ unsigned short f2bf(float f) {
    union { float f; unsigned int u; } v; v.f = f;
    unsigned int r = (v.u + 0x7fffu + ((v.u >> 16) & 1u)) >> 16;  // RNE
    return (unsigned short)r;
}
__device__ __forceinline__ float bf2f(unsigned short b) {
    union { unsigned int u; float f; } v; v.u = ((unsigned int)b) << 16;
    return v.f;
}

__device__ __forceinline__ int lower_bound_i(const int* __restrict__ a, int n, int v) {
    int lo = 0, hi = n;
    while (lo < hi) { int m = (lo + hi) >> 1; if (a[m] < v) lo = m + 1; else hi = m; }
    return lo;
}

// ---------------- zero counts+sums (replaces 43µs runtime fillBuffer) --------
__global__ void k_zero(int4* __restrict__ p) {
    int i = blockIdx.x * blockDim.x + threadIdx.x;
    if (i < ZERO_INT4) p[i] = make_int4(0, 0, 0, 0);
}

// ---------------- CSR build (8-edge ILP per thread) ----------------
__global__ void k_count(const int* __restrict__ dst, int* __restrict__ cnt) {
    const int base = (blockIdx.x * blockDim.x + threadIdx.x) * 8;
    if (base + 8 <= N_EDGES) {
        int4 a = *(const int4*)(dst + base);
        int4 b = *(const int4*)(dst + base + 4);
        atomicAdd(&cnt[a.x], 1); atomicAdd(&cnt[a.y], 1);
        atomicAdd(&cnt[a.z], 1); atomicAdd(&cnt[a.w], 1);
        atomicAdd(&cnt[b.x], 1); atomicAdd(&cnt[b.y], 1);
        atomicAdd(&cnt[b.z], 1); atomicAdd(&cnt[b.w], 1);
    } else {
        for (int e = base; e < N_EDGES; ++e) atomicAdd(&cnt[dst[e]], 1);
    }
}

__global__ void k_fill(const int* __restrict__ src, const int* __restrict__ dst,
                       int* __restrict__ cursor, int* __restrict__ csr_src) {
    const int base = (blockIdx.x * blockDim.x + threadIdx.x) * 8;
    if (base + 8 <= N_EDGES) {
        int4 da = *(const int4*)(dst + base);
        int4 db = *(const int4*)(dst + base + 4);
        int4 sa = *(const int4*)(src + base);
        int4 sb = *(const int4*)(src + base + 4);
        int p0 = atomicAdd(&cursor[da.x], 1);
        int p1 = atomicAdd(&cursor[da.y], 1);
        int p2 = atomicAdd(&cursor[da.z], 1);
        int p3 = atomicAdd(&cursor[da.w], 1);
        int p4 = atomicAdd(&cursor[db.x], 1);
        int p5 = atomicAdd(&cursor[db.y], 1);
        int p6 = atomicAdd(&cursor[db.z], 1);
        int p7 = atomicAdd(&cursor[db.w], 1);
        csr_src[p0] = sa.x; csr_src[p1] = sa.y;
        csr_src[p2] = sa.z; csr_src[p3] = sa.w;
        csr_src[p4] = sb.x; csr_src[p5] = sb.y;
        csr_src[p6] = sb.z; csr_src[p7] = sb.w;
    } else {
        for (int e = base; e < N_EDGES; ++e) {
            int p = atomicAdd(&cursor[dst[e]], 1);
            csr_src[p] = src[e];
        }
    }
}

__global__ __launch_bounds__(SCAN_BS) void k_scan1(const int* __restrict__ cnt,
                                                   int* __restrict__ local_pref,
                                                   int* __restrict__ blk_sum) {
    const int t = threadIdx.x;
    const int gid = blockIdx.x * SCAN_BS + t;
    const int lane = t & 63, w = t >> 6;
    int v = (gid < N_NODES) ? cnt[gid] : 0;
    int x = v;
#pragma unroll
    for (int off = 1; off < 64; off <<= 1) {
        int y = __shfl_up(x, off, 64);
        if (lane >= off) x += y;
    }
    __shared__ int wsum[SCAN_BS / 64];
    __shared__ int wpre[SCAN_BS / 64];
    if (lane == 63) wsum[w] = x;
    __syncthreads();
    if (t == 0) {
        int run = 0;
#pragma unroll
        for (int i = 0; i < SCAN_BS / 64; ++i) { wpre[i] = run; run += wsum[i]; }
    }
    __syncthreads();
    int excl = x - v + wpre[w];
    if (gid < N_NODES) local_pref[gid] = excl;
    if (t == SCAN_BS - 1) blk_sum[blockIdx.x] = excl + v;
}

__global__ __launch_bounds__(128) void k_scan2(const int* __restrict__ blk_sum,
                                               int* __restrict__ blk_base,
                                               int* __restrict__ row_start) {
    const int t = threadIdx.x;
    const int lane = t & 63;
    int v = (t < SCAN_NB) ? blk_sum[t] : 0;
    int x = v;
#pragma unroll
    for (int off = 1; off < 64; off <<= 1) {
        int y = __shfl_up(x, off, 64);
        if (lane >= off) x += y;
    }
    __shared__ int wsum0;
    if (t == 63) wsum0 = x;
    __syncthreads();
    int excl = x - v + ((t >= 64) ? wsum0 : 0);
    if (t < SCAN_NB) blk_base[t] = excl;
    if (t == 127) row_start[N_NODES] = excl + v;  // grand total
}

__global__ __launch_bounds__(SCAN_BS) void k_scan3(const int* __restrict__ local_pref,
                                                   const int* __restrict__ blk_base,
                                                   int* __restrict__ row_start,
                                                   int* __restrict__ cursor) {
    const int gid = blockIdx.x * SCAN_BS + threadIdx.x;
    if (gid < N_NODES) {
        int r = local_pref[gid] + blk_base[blockIdx.x];
        row_start[gid] = r;
        cursor[gid] = r;
    }
}

// ---------------- Layer 1 logits: a_s/a_d per node (h1 NOT materialized) -----
__global__ __launch_bounds__(256) void k_gemm1(const float* __restrict__ x,
                                               const float* __restrict__ W1,
                                               const float* __restrict__ att_s,
                                               const float* __restrict__ att_d,
                                               float4* __restrict__ a_s,
                                               float4* __restrict__ a_d) {
    __shared__ float Ws[5 * 256];
    const int t = threadIdx.x;
    for (int i = t; i < 5 * 256; i += 256) Ws[i] = W1[i];
    __syncthreads();
    const int wave = t >> 6, lane = t & 63;
    const int n = blockIdx.x * 4 + wave;
    if (n >= N_NODES) return;
    float x0 = x[n * 5 + 0], x1 = x[n * 5 + 1], x2 = x[n * 5 + 2],
          x3 = x[n * 5 + 3], x4 = x[n * 5 + 4];
    float vs[4], vd[4];
#pragma unroll
    for (int hd = 0; hd < 4; ++hd) {
        const int c = hd * 64 + lane;
        float h = x0 * Ws[c] + x1 * Ws[256 + c] + x2 * Ws[512 + c] +
                  x3 * Ws[768 + c] + x4 * Ws[1024 + c];
        vs[hd] = h * att_s[c];
        vd[hd] = h * att_d[c];
    }
#pragma unroll
    for (int off = 32; off; off >>= 1) {
#pragma unroll
        for (int hd = 0; hd < 4; ++hd) {
            vs[hd] += __shfl_xor(vs[hd], off, 64);
            vd[hd] += __shfl_xor(vd[hd], off, 64);
        }
    }
    if (lane == 0) {
        a_s[n] = make_float4(vs[0], vs[1], vs[2], vs[3]);
        a_d[n] = make_float4(vd[0], vd[1], vd[2], vd[3]);
    }
}

// ---------------- Layer 1 aggregation: SUM-SWAPPED ----------------
__global__ __launch_bounds__(256) void k_agg1(const float* __restrict__ x,
                                              const float* __restrict__ W1,
                                              const float4* __restrict__ asv,
                                              const float4* __restrict__ adv,
                                              const int* __restrict__ row_start,
                                              const int* __restrict__ csr_src,
                                              const float* __restrict__ b1,
                                              unsigned short* __restrict__ out1rm) {
    __shared__ float hand[4][4][24];   // [wave][grp][4 den + 20 Xw]
    const int t = threadIdx.x;
    const int wave = t >> 6, lane = t & 63;
    const int grp = lane >> 4, l16 = lane & 15;
    const int d = blockIdx.x * 16 + wave * 4 + grp;   // exact cover

    float w1r[4][5], bias[4];
#pragma unroll
    for (int h = 0; h < 4; ++h) {
#pragma unroll
        for (int i = 0; i < 5; ++i) w1r[h][i] = W1[i * 256 + h * 64 + lane];
        bias[h] = b1[h * 64 + lane];
    }

    const int beg = row_start[d], end = row_start[d + 1];
    const float4 ad = adv[d];

    float den[4] = {0.f, 0.f, 0.f, 0.f};
    float xw[4][5];
#pragma unroll
    for (int h = 0; h < 4; ++h)
#pragma unroll
        for (int i = 0; i < 5; ++i) xw[h][i] = 0.f;

    for (int cb = beg; cb < end; cb += 16) {
        const int j = cb + l16;
        if (j < end) {
            const int s = csr_src[j];
            const float4 a = asv[s];
            float w[4];
            w[0] = __expf(lrelu(a.x + ad.x));
            w[1] = __expf(lrelu(a.y + ad.y));
            w[2] = __expf(lrelu(a.z + ad.z));
            w[3] = __expf(lrelu(a.w + ad.w));
            const float* xp = x + (size_t)s * 5;
            float xv[5];
#pragma unroll
            for (int i = 0; i < 5; ++i) xv[i] = xp[i];
#pragma unroll
            for (int h = 0; h < 4; ++h) {
                den[h] += w[h];
#pragma unroll
                for (int i = 0; i < 5; ++i) xw[h][i] += w[h] * xv[i];
            }
        }
    }

#pragma unroll
    for (int off = 1; off < 16; off <<= 1) {
#pragma unroll
        for (int h = 0; h < 4; ++h) {
            den[h] += __shfl_xor(den[h], off, 64);
#pragma unroll
            for (int i = 0; i < 5; ++i) xw[h][i] += __shfl_xor(xw[h][i], off, 64);
        }
    }

    {   // self loop
        const float4 as = asv[d];
        float w[4];
        w[0] = __expf(lrelu(as.x + ad.x));
        w[1] = __expf(lrelu(as.y + ad.y));
        w[2] = __expf(lrelu(as.z + ad.z));
        w[3] = __expf(lrelu(as.w + ad.w));
        const float* xp = x + (size_t)d * 5;
        float xv[5];
#pragma unroll
        for (int i = 0; i < 5; ++i) xv[i] = xp[i];
#pragma unroll
        for (int h = 0; h < 4; ++h) {
            den[h] += w[h];
#pragma unroll
            for (int i = 0; i < 5; ++i) xw[h][i] += w[h] * xv[i];
        }
    }

    if (l16 == 0) {
#pragma unroll
        for (int h = 0; h < 4; ++h) hand[wave][grp][h] = den[h];
#pragma unroll
        for (int h = 0; h < 4; ++h)
#pragma unroll
            for (int i = 0; i < 5; ++i) hand[wave][grp][4 + h * 5 + i] = xw[h][i];
    }
    __syncthreads();

#pragma unroll
    for (int n = 0; n < 4; ++n) {
        const int dn = blockIdx.x * 16 + wave * 4 + n;
        unsigned short* op = out1rm + (size_t)dn * 256;
#pragma unroll
        for (int h = 0; h < 4; ++h) {
            const float dh = hand[wave][n][h] + 1e-16f;
            float hh = hand[wave][n][4 + h * 5 + 0] * w1r[h][0]
                     + hand[wave][n][4 + h * 5 + 1] * w1r[h][1]
                     + hand[wave][n][4 + h * 5 + 2] * w1r[h][2]
                     + hand[wave][n][4 + h * 5 + 3] * w1r[h][3]
                     + hand[wave][n][4 + h * 5 + 4] * w1r[h][4];
            op[h * 64 + lane] = f2bf(fmaxf(hh / dh + bias[h], 0.f));
        }
    }
}

// ---------------- Layer 2: MFMA GEMM (50000x256 @ 256x64) + attention logits ----
__global__ __launch_bounds__(256) void k_gemm2(const unsigned short* __restrict__ in,
                                               const float* __restrict__ W2,
                                               const float* __restrict__ att_s2,
                                               const float* __restrict__ att_d2,
                                               unsigned short* __restrict__ h2b,
                                               float* __restrict__ a_s2,
                                               float* __restrict__ a_d2) {
    __shared__ unsigned short lW[16384];  // 32 KB: [s][g][t][c16][j]
    const int t = threadIdx.x;
    for (int idx = t; idx < 16384; idx += 256) {
        int j = idx & 7, c16 = (idx >> 3) & 15, tt = (idx >> 7) & 3,
            g = (idx >> 9) & 3, s = idx >> 11;
        int k = 32 * s + 8 * g + j, c = 16 * tt + c16;
        lW[idx] = f2bf(W2[k * 64 + c]);
    }
    __syncthreads();
    const int wave = t >> 6, lane = t & 63;
    const int g = lane >> 4, c16 = lane & 15;
    const int nb = blockIdx.x * 64 + wave * 16;
    if (nb >= N_NODES) return;

    f32x4 acc[4];
#pragma unroll
    for (int i = 0; i < 4; ++i) acc[i] = (f32x4){0.f, 0.f, 0.f, 0.f};

    const unsigned short* arow = in + (size_t)(nb + c16) * 256;  // A row = lane&15
#pragma unroll
    for (int s = 0; s < 8; ++s) {
        short8 a = *reinterpret_cast<const short8*>(arow + 32 * s + 8 * g);
#pragma unroll
        for (int tt = 0; tt < 4; ++tt) {
            short8 b = *reinterpret_cast<const short8*>(
                lW + ((((s * 4 + g) * 4 + tt) * 16 + c16) << 3));
            acc[tt] = __builtin_amdgcn_mfma_f32_16x16x32_bf16(a, b, acc[tt], 0, 0, 0);
        }
    }

    float attS[4], attD[4];
#pragma unroll
    for (int tt = 0; tt < 4; ++tt) {
        attS[tt] = att_s2[16 * tt + c16];
        attD[tt] = att_d2[16 * tt + c16];
    }
#pragma unroll
    for (int r = 0; r < 4; ++r) {
        const int node = nb + g * 4 + r;
        const bool ok = node < N_NODES;
        float vs = 0.f, vd = 0.f;
#pragma unroll
        for (int tt = 0; tt < 4; ++tt) {
            float v = acc[tt][r];
            if (ok) h2b[(size_t)node * 64 + 16 * tt + c16] = f2bf(v);
            vs += v * attS[tt];
            vd += v * attD[tt];
        }
#pragma unroll
        for (int off = 1; off < 16; off <<= 1) {
            vs += __shfl_xor(vs, off, 64);
            vd += __shfl_xor(vd, off, 64);
        }
        if (ok && c16 == 0) { a_s2[node] = vs; a_d2[node] = vd; }
    }
}

// ---------------- Layer 2 aggregation + fused pool (replicated accumulators) --
__global__ __launch_bounds__(256) void k_agg2(const unsigned short* __restrict__ h2b,
                                              const float* __restrict__ as_,
                                              const float* __restrict__ ad_,
                                              const int* __restrict__ row_start,
                                              const int* __restrict__ csr_src,
                                              const float* __restrict__ b2,
                                              const int* __restrict__ batch,
                                              float* __restrict__ sums) {
    const int wave = threadIdx.x >> 6, lane = threadIdx.x & 63;
    const int d = blockIdx.x * 4 + wave;
    if (d >= N_NODES) return;
    const int beg = row_start[d], end = row_start[d + 1];
    const float adl = ad_[d];

    float den, acc;
    {
        float w = __expf(lrelu(as_[d] + adl));
        den = (lane == 0) ? w : 0.f;
        acc = w * bf2f(h2b[(size_t)d * 64 + lane]);
    }
    for (int c = beg; c < end; c += 64) {
        int rem = end - c; if (rem > 64) rem = 64;
        int sreg = 0;
        float wr = 0.f;
        if (lane < rem) {
            sreg = csr_src[c + lane];
            wr = __expf(lrelu(as_[sreg] + adl));
            den += wr;
        }
        int e = 0;
        for (; e + 8 <= rem; e += 8) {
            int sq[8];
#pragma unroll
            for (int q = 0; q < 8; ++q) sq[q] = __shfl(sreg, e + q, 64);
            unsigned short vq[8];
#pragma unroll
            for (int q = 0; q < 8; ++q) vq[q] = h2b[(size_t)sq[q] * 64 + lane];
#pragma unroll
            for (int q = 0; q < 8; ++q) {
                acc += __shfl(wr, e + q, 64) * bf2f(vq[q]);
            }
        }
        for (; e < rem; ++e) {
            int s = __shfl(sreg, e, 64);
            acc += __shfl(wr, e, 64) * bf2f(h2b[(size_t)s * 64 + lane]);
        }
    }
#pragma unroll
    for (int off = 32; off; off >>= 1) den += __shfl_xor(den, off, 64);
    float val = fmaxf(acc / (den + 1e-16f) + b2[lane], 0.f);
    const int rep = blockIdx.x & (N_REP - 1);
    atomicAdd(&sums[(size_t)rep * (N_GRAPHS * 64) + batch[d] * 64 + lane], val);
}

// ---------------- Final: reduce replicas + mean + 64->2 linear ----------------
__global__ __launch_bounds__(64) void k_final(const float* __restrict__ sums,
                                              const int* __restrict__ batch,
                                              const float* __restrict__ linW,
                                              const float* __restrict__ linb,
                                              float* __restrict__ out) {
    const int g = blockIdx.x;
    const int lane = threadIdx.x;
    float s = 0.f;
#pragma unroll 8
    for (int r = 0; r < N_REP; ++r)
        s += sums[(size_t)r * (N_GRAPHS * 64) + g * 64 + lane];
    int beg = lower_bound_i(batch, N_NODES, g);
    int end = lower_bound_i(batch, N_NODES, g + 1);
    float val = s / fmaxf((float)(end - beg), 1.0f);
    float v0 = val * linW[lane * 2 + 0];
    float v1 = val * linW[lane * 2 + 1];
#pragma unroll
    for (int off = 32; off; off >>= 1) {
        v0 += __shfl_xor(v0, off, 64);
        v1 += __shfl_xor(v1, off, 64);
    }
    if (lane == 0) {
        out[g * 2 + 0] = v0 + linb[0];
        out[g * 2 + 1] = v1 + linb[1];
    }
}

extern "C" void kernel_launch(void* const* d_in, const int* in_sizes, int n_in,
                              void* d_out, int out_size, void* d_ws, size_t ws_size,
                              hipStream_t stream) {
    const float* x    = (const float*)d_in[0];
    const int*   ei   = (const int*)d_in[1];
    const int*   bat  = (const int*)d_in[2];
    const float* W1   = (const float*)d_in[3];
    const float* as1  = (const float*)d_in[4];
    const float* ad1  = (const float*)d_in[5];
    const float* b1   = (const float*)d_in[6];
    const float* W2   = (const float*)d_in[7];
    const float* as2  = (const float*)d_in[8];
    const float* ad2  = (const float*)d_in[9];
    const float* b2   = (const float*)d_in[10];
    const float* linW = (const float*)d_in[11];
    const float* linb = (const float*)d_in[12];
    float* out = (float*)d_out;

    const int* src = ei;
    const int* dst = ei + N_EDGES;

    char* w = (char*)d_ws;
    unsigned short* out1rm = (unsigned short*)w; w += (size_t)N_NODES * 256 * 2;
    float4* a_s1 = (float4*)w; w += (size_t)N_NODES * 16;
    float4* a_d1 = (float4*)w; w += (size_t)N_NODES * 16;
    unsigned short* h2b = (unsigned short*)w; w += (size_t)N_NODES * 64 * 2;
    float* a_s2  = (float*)w; w += (size_t)N_NODES * 4;
    float* a_d2  = (float*)w; w += (size_t)N_NODES * 4;
    // counts + sums adjacent: ONE k_zero covers both
    int* counts  = (int*)w;   w += (size_t)N_NODES * 4;
    float* sums  = (float*)w; w += (size_t)N_REP * N_GRAPHS * 64 * 4;
    int* row_start = (int*)w; w += (size_t)(N_NODES + 64) * 4;
    int* cursor    = (int*)w; w += (size_t)N_NODES * 4;
    int* csr_src   = (int*)w; w += (size_t)N_EDGES * 4;
    int* blk_sum   = (int*)w; w += 128 * 4;
    int* blk_base  = (int*)w; w += 128 * 4;

    // CSR build (multi-block scan); k_zero replaces hipMemsetAsync (SDMA overhead)
    k_zero<<<(ZERO_INT4 + 255) / 256, 256, 0, stream>>>((int4*)counts);
    k_count<<<(N_EDGES / 8 + 255) / 256, 256, 0, stream>>>(dst, counts);
    k_scan1<<<SCAN_NB, SCAN_BS, 0, stream>>>(counts, cursor, blk_sum);
    k_scan2<<<1, 128, 0, stream>>>(blk_sum, blk_base, row_start);
    k_scan3<<<SCAN_NB, SCAN_BS, 0, stream>>>(cursor, blk_base, row_start, cursor);
    k_fill<<<(N_EDGES / 8 + 255) / 256, 256, 0, stream>>>(src, dst, cursor, csr_src);

    // Layer 1
    k_gemm1<<<(N_NODES + 3) / 4, 256, 0, stream>>>(x, W1, as1, ad1, a_s1, a_d1);
    k_agg1<<<N_NODES / 16, 256, 0, stream>>>(x, W1, a_s1, a_d1, row_start, csr_src, b1, out1rm);
    // Layer 2 (MFMA)
    k_gemm2<<<(N_NODES + 63) / 64, 256, 0, stream>>>(out1rm, W2, as2, ad2, h2b, a_s2, a_d2);
    k_agg2<<<(N_NODES + 3) / 4, 256, 0, stream>>>(h2b, a_s2, a_d2, row_start, csr_src, b2,
                                                  bat, sums);
    // Reduce replicas + mean + linear
    k_final<<<N_GRAPHS, 64, 0, stream>>>(sums, bat, linW, linb, out);
}

// Round 15
// 208.071 us; speedup vs baseline: 1.3120x; 1.0349x over previous
//
#include <hip/hip_runtime.h>
#include <math.h>

#define N_NODES 50000
#define N_EDGES 800000
#define N_GRAPHS 64
#define NEG_SLOPE 0.2f
#define SCAN_BS 512
#define SCAN_NB ((N_NODES + SCAN_BS - 1) / SCAN_BS)   // 98
#define N_REP 64   // pooled-sum replicas (contention breaker)
#define ZERO_INT4 ((N_NODES * 4 + N_REP * N_GRAPHS * 64 * 4) / 16)

typedef __attribute__((ext_vector_type(8))) short short8;
typedef __attribute__((ext_vector_type(4))) float f32x4;

__device__ __forceinline__ float lrelu(float x) { return x > 0.f ? x : NEG_SLOPE * x; }

__device__ __forceinline__ unsigned short f2bf(float f) {
    union { float f; unsigned int u; } v; v.f = f;
    unsigned int r = (v.u + 0x7fffu + ((v.u >> 16) & 1u)) >> 16;  // RNE
    return (unsigned short)r;
}
__device__ __forceinline__ float bf2f(unsigned short b) {
    union { unsigned int u; float f; } v; v.u = ((unsigned int)b) << 16;
    return v.f;
}
__device__ __forceinline__ float bfLO(unsigned int u) {
    union { unsigned int u; float f; } v; v.u = u << 16;
    return v.f;
}
__device__ __forceinline__ float bfHI(unsigned int u) {
    union { unsigned int u; float f; } v; v.u = u & 0xffff0000u;
    return v.f;
}

__device__ __forceinline__ int lower_bound_i(const int* __restrict__ a, int n, int v) {
    int lo = 0, hi = n;
    while (lo < hi) { int m = (lo + hi) >> 1; if (a[m] < v) lo = m + 1; else hi = m; }
    return lo;
}

// ---------------- zero counts+sums ----------------
__global__ void k_zero(int4* __restrict__ p) {
    int i = blockIdx.x * blockDim.x + threadIdx.x;
    if (i < ZERO_INT4) p[i] = make_int4(0, 0, 0, 0);
}

// ---------------- CSR build: count + per-edge rank (atomic pass) ----------------
__global__ void k_countrank(const int* __restrict__ dst, int* __restrict__ cnt,
                            int* __restrict__ rank) {
    const int base = (blockIdx.x * blockDim.x + threadIdx.x) * 4;
    if (base + 4 <= N_EDGES) {
        int4 d4 = *(const int4*)(dst + base);
        int4 r;
        r.x = atomicAdd(&cnt[d4.x], 1);
        r.y = atomicAdd(&cnt[d4.y], 1);
        r.z = atomicAdd(&cnt[d4.z], 1);
        r.w = atomicAdd(&cnt[d4.w], 1);
        *(int4*)(rank + base) = r;
    } else {
        for (int e = base; e < N_EDGES; ++e) rank[e] = atomicAdd(&cnt[dst[e]], 1);
    }
}

// ---------------- CSR build: atomic-free scatter ----------------
__global__ void k_scatter(const int* __restrict__ src, const int* __restrict__ dst,
                          const int* __restrict__ rank, const int* __restrict__ row_start,
                          int* __restrict__ csr_src) {
    const int base = (blockIdx.x * blockDim.x + threadIdx.x) * 4;
    if (base + 4 <= N_EDGES) {
        int4 d4 = *(const int4*)(dst + base);
        int4 s4 = *(const int4*)(src + base);
        int4 r4 = *(const int4*)(rank + base);
        csr_src[row_start[d4.x] + r4.x] = s4.x;
        csr_src[row_start[d4.y] + r4.y] = s4.y;
        csr_src[row_start[d4.z] + r4.z] = s4.z;
        csr_src[row_start[d4.w] + r4.w] = s4.w;
    } else {
        for (int e = base; e < N_EDGES; ++e)
            csr_src[row_start[dst[e]] + rank[e]] = src[e];
    }
}

__global__ __launch_bounds__(SCAN_BS) void k_scan1(const int* __restrict__ cnt,
                                                   int* __restrict__ local_pref,
                                                   int* __restrict__ blk_sum) {
    const int t = threadIdx.x;
    const int gid = blockIdx.x * SCAN_BS + t;
    const int lane = t & 63, w = t >> 6;
    int v = (gid < N_NODES) ? cnt[gid] : 0;
    int x = v;
#pragma unroll
    for (int off = 1; off < 64; off <<= 1) {
        int y = __shfl_up(x, off, 64);
        if (lane >= off) x += y;
    }
    __shared__ int wsum[SCAN_BS / 64];
    __shared__ int wpre[SCAN_BS / 64];
    if (lane == 63) wsum[w] = x;
    __syncthreads();
    if (t == 0) {
        int run = 0;
#pragma unroll
        for (int i = 0; i < SCAN_BS / 64; ++i) { wpre[i] = run; run += wsum[i]; }
    }
    __syncthreads();
    int excl = x - v + wpre[w];
    if (gid < N_NODES) local_pref[gid] = excl;
    if (t == SCAN_BS - 1) blk_sum[blockIdx.x] = excl + v;
}

__global__ __launch_bounds__(128) void k_scan2(const int* __restrict__ blk_sum,
                                               int* __restrict__ blk_base,
                                               int* __restrict__ row_start) {
    const int t = threadIdx.x;
    const int lane = t & 63;
    int v = (t < SCAN_NB) ? blk_sum[t] : 0;
    int x = v;
#pragma unroll
    for (int off = 1; off < 64; off <<= 1) {
        int y = __shfl_up(x, off, 64);
        if (lane >= off) x += y;
    }
    __shared__ int wsum0;
    if (t == 63) wsum0 = x;
    __syncthreads();
    int excl = x - v + ((t >= 64) ? wsum0 : 0);
    if (t < SCAN_NB) blk_base[t] = excl;
    if (t == 127) row_start[N_NODES] = excl + v;  // grand total
}

__global__ __launch_bounds__(SCAN_BS) void k_scan3(const int* __restrict__ local_pref,
                                                   const int* __restrict__ blk_base,
                                                   int* __restrict__ row_start) {
    const int gid = blockIdx.x * SCAN_BS + threadIdx.x;
    if (gid < N_NODES) row_start[gid] = local_pref[gid] + blk_base[blockIdx.x];
}

// ---------------- Layer 1 logits: a_s/a_d per node (h1 NOT materialized) -----
__global__ __launch_bounds__(256) void k_gemm1(const float* __restrict__ x,
                                               const float* __restrict__ W1,
                                               const float* __restrict__ att_s,
                                               const float* __restrict__ att_d,
                                               float4* __restrict__ a_s,
                                               float4* __restrict__ a_d) {
    __shared__ float Ws[5 * 256];
    const int t = threadIdx.x;
    for (int i = t; i < 5 * 256; i += 256) Ws[i] = W1[i];
    __syncthreads();
    const int wave = t >> 6, lane = t & 63;
    const int n = blockIdx.x * 4 + wave;
    if (n >= N_NODES) return;
    float x0 = x[n * 5 + 0], x1 = x[n * 5 + 1], x2 = x[n * 5 + 2],
          x3 = x[n * 5 + 3], x4 = x[n * 5 + 4];
    float vs[4], vd[4];
#pragma unroll
    for (int hd = 0; hd < 4; ++hd) {
        const int c = hd * 64 + lane;
        float h = x0 * Ws[c] + x1 * Ws[256 + c] + x2 * Ws[512 + c] +
                  x3 * Ws[768 + c] + x4 * Ws[1024 + c];
        vs[hd] = h * att_s[c];
        vd[hd] = h * att_d[c];
    }
#pragma unroll
    for (int off = 32; off; off >>= 1) {
#pragma unroll
        for (int hd = 0; hd < 4; ++hd) {
            vs[hd] += __shfl_xor(vs[hd], off, 64);
            vd[hd] += __shfl_xor(vd[hd], off, 64);
        }
    }
    if (lane == 0) {
        a_s[n] = make_float4(vs[0], vs[1], vs[2], vs[3]);
        a_d[n] = make_float4(vd[0], vd[1], vd[2], vd[3]);
    }
}

// ---------------- Layer 1 aggregation: SUM-SWAPPED ----------------
__global__ __launch_bounds__(256) void k_agg1(const float* __restrict__ x,
                                              const float* __restrict__ W1,
                                              const float4* __restrict__ asv,
                                              const float4* __restrict__ adv,
                                              const int* __restrict__ row_start,
                                              const int* __restrict__ csr_src,
                                              const float* __restrict__ b1,
                                              unsigned short* __restrict__ out1rm) {
    __shared__ float hand[4][4][24];   // [wave][grp][4 den + 20 Xw]
    const int t = threadIdx.x;
    const int wave = t >> 6, lane = t & 63;
    const int grp = lane >> 4, l16 = lane & 15;
    const int d = blockIdx.x * 16 + wave * 4 + grp;   // exact cover

    float w1r[4][5], bias[4];
#pragma unroll
    for (int h = 0; h < 4; ++h) {
#pragma unroll
        for (int i = 0; i < 5; ++i) w1r[h][i] = W1[i * 256 + h * 64 + lane];
        bias[h] = b1[h * 64 + lane];
    }

    const int beg = row_start[d], end = row_start[d + 1];
    const float4 ad = adv[d];

    float den[4] = {0.f, 0.f, 0.f, 0.f};
    float xw[4][5];
#pragma unroll
    for (int h = 0; h < 4; ++h)
#pragma unroll
        for (int i = 0; i < 5; ++i) xw[h][i] = 0.f;

    for (int cb = beg; cb < end; cb += 16) {
        const int j = cb + l16;
        if (j < end) {
            const int s = csr_src[j];
            const float4 a = asv[s];
            float w[4];
            w[0] = __expf(lrelu(a.x + ad.x));
            w[1] = __expf(lrelu(a.y + ad.y));
            w[2] = __expf(lrelu(a.z + ad.z));
            w[3] = __expf(lrelu(a.w + ad.w));
            const float* xp = x + (size_t)s * 5;
            float xv[5];
#pragma unroll
            for (int i = 0; i < 5; ++i) xv[i] = xp[i];
#pragma unroll
            for (int h = 0; h < 4; ++h) {
                den[h] += w[h];
#pragma unroll
                for (int i = 0; i < 5; ++i) xw[h][i] += w[h] * xv[i];
            }
        }
    }

#pragma unroll
    for (int off = 1; off < 16; off <<= 1) {
#pragma unroll
        for (int h = 0; h < 4; ++h) {
            den[h] += __shfl_xor(den[h], off, 64);
#pragma unroll
            for (int i = 0; i < 5; ++i) xw[h][i] += __shfl_xor(xw[h][i], off, 64);
        }
    }

    {   // self loop
        const float4 as = asv[d];
        float w[4];
        w[0] = __expf(lrelu(as.x + ad.x));
        w[1] = __expf(lrelu(as.y + ad.y));
        w[2] = __expf(lrelu(as.z + ad.z));
        w[3] = __expf(lrelu(as.w + ad.w));
        const float* xp = x + (size_t)d * 5;
        float xv[5];
#pragma unroll
        for (int i = 0; i < 5; ++i) xv[i] = xp[i];
#pragma unroll
        for (int h = 0; h < 4; ++h) {
            den[h] += w[h];
#pragma unroll
            for (int i = 0; i < 5; ++i) xw[h][i] += w[h] * xv[i];
        }
    }

    if (l16 == 0) {
#pragma unroll
        for (int h = 0; h < 4; ++h) hand[wave][grp][h] = den[h];
#pragma unroll
        for (int h = 0; h < 4; ++h)
#pragma unroll
            for (int i = 0; i < 5; ++i) hand[wave][grp][4 + h * 5 + i] = xw[h][i];
    }
    __syncthreads();

#pragma unroll
    for (int n = 0; n < 4; ++n) {
        const int dn = blockIdx.x * 16 + wave * 4 + n;
        unsigned short* op = out1rm + (size_t)dn * 256;
#pragma unroll
        for (int h = 0; h < 4; ++h) {
            const float dh = hand[wave][n][h] + 1e-16f;
            float hh = hand[wave][n][4 + h * 5 + 0] * w1r[h][0]
                     + hand[wave][n][4 + h * 5 + 1] * w1r[h][1]
                     + hand[wave][n][4 + h * 5 + 2] * w1r[h][2]
                     + hand[wave][n][4 + h * 5 + 3] * w1r[h][3]
                     + hand[wave][n][4 + h * 5 + 4] * w1r[h][4];
            op[h * 64 + lane] = f2bf(fmaxf(hh / dh + bias[h], 0.f));
        }
    }
}

// ---------------- Layer 2: MFMA GEMM (50000x256 @ 256x64) + attention logits ----
__global__ __launch_bounds__(256) void k_gemm2(const unsigned short* __restrict__ in,
                                               const float* __restrict__ W2,
                                               const float* __restrict__ att_s2,
                                               const float* __restrict__ att_d2,
                                               unsigned short* __restrict__ h2b,
                                               float* __restrict__ a_s2,
                                               float* __restrict__ a_d2) {
    __shared__ unsigned short lW[16384];  // 32 KB: [s][g][t][c16][j]
    const int t = threadIdx.x;
    for (int idx = t; idx < 16384; idx += 256) {
        int j = idx & 7, c16 = (idx >> 3) & 15, tt = (idx >> 7) & 3,
            g = (idx >> 9) & 3, s = idx >> 11;
        int k = 32 * s + 8 * g + j, c = 16 * tt + c16;
        lW[idx] = f2bf(W2[k * 64 + c]);
    }
    __syncthreads();
    const int wave = t >> 6, lane = t & 63;
    const int g = lane >> 4, c16 = lane & 15;
    const int nb = blockIdx.x * 64 + wave * 16;
    if (nb >= N_NODES) return;

    f32x4 acc[4];
#pragma unroll
    for (int i = 0; i < 4; ++i) acc[i] = (f32x4){0.f, 0.f, 0.f, 0.f};

    const unsigned short* arow = in + (size_t)(nb + c16) * 256;  // A row = lane&15
#pragma unroll
    for (int s = 0; s < 8; ++s) {
        short8 a = *reinterpret_cast<const short8*>(arow + 32 * s + 8 * g);
#pragma unroll
        for (int tt = 0; tt < 4; ++tt) {
            short8 b = *reinterpret_cast<const short8*>(
                lW + ((((s * 4 + g) * 4 + tt) * 16 + c16) << 3));
            acc[tt] = __builtin_amdgcn_mfma_f32_16x16x32_bf16(a, b, acc[tt], 0, 0, 0);
        }
    }

    float attS[4], attD[4];
#pragma unroll
    for (int tt = 0; tt < 4; ++tt) {
        attS[tt] = att_s2[16 * tt + c16];
        attD[tt] = att_d2[16 * tt + c16];
    }
#pragma unroll
    for (int r = 0; r < 4; ++r) {
        const int node = nb + g * 4 + r;
        const bool ok = node < N_NODES;
        float vs = 0.f, vd = 0.f;
#pragma unroll
        for (int tt = 0; tt < 4; ++tt) {
            float v = acc[tt][r];
            if (ok) h2b[(size_t)node * 64 + 16 * tt + c16] = f2bf(v);
            vs += v * attS[tt];
            vd += v * attD[tt];
        }
#pragma unroll
        for (int off = 1; off < 16; off <<= 1) {
            vs += __shfl_xor(vs, off, 64);
            vd += __shfl_xor(vd, off, 64);
        }
        if (ok && c16 == 0) { a_s2[node] = vs; a_d2[node] = vd; }
    }
}

// ---------------- Layer 2 aggregation + fused pool ----------------
// Gather vectorized: lane = (edge-half, channel-pair). Each lane loads a uint
// (2 bf16 channels); halves process alternating edges; shfl_xor(32) merges.
__global__ __launch_bounds__(256) void k_agg2(const unsigned short* __restrict__ h2b,
                                              const float* __restrict__ as_,
                                              const float* __restrict__ ad_,
                                              const int* __restrict__ row_start,
                                              const int* __restrict__ csr_src,
                                              const float* __restrict__ b2,
                                              const int* __restrict__ batch,
                                              float* __restrict__ sums) {
    const unsigned int* h2u = (const unsigned int*)h2b;
    const int wave = threadIdx.x >> 6, lane = threadIdx.x & 63;
    const int m = lane & 31, half = lane >> 5;
    const int d = blockIdx.x * 4 + wave;
    if (d >= N_NODES) return;
    const int beg = row_start[d], end = row_start[d + 1];
    const float adl = ad_[d];

    float den;
    float accx = 0.f, accy = 0.f;
    {   // self loop (half 0 only for acc; lane 0 only for den)
        float w = __expf(lrelu(as_[d] + adl));
        den = (lane == 0) ? w : 0.f;
        if (half == 0) {
            unsigned int v = h2u[(size_t)d * 32 + m];
            accx = w * bfLO(v); accy = w * bfHI(v);
        }
    }
    for (int c = beg; c < end; c += 64) {
        int rem = end - c; if (rem > 64) rem = 64;
        int sreg = 0;
        float wr = 0.f;
        if (lane < rem) {
            sreg = csr_src[c + lane];
            wr = __expf(lrelu(as_[sreg] + adl));
            den += wr;
        }
        int e = 0;
        for (; e + 8 <= rem; e += 8) {   // 4 pairs in flight
            int e0 = e + half, e1 = e + 2 + half, e2 = e + 4 + half, e3 = e + 6 + half;
            int s0 = __shfl(sreg, e0, 64), s1 = __shfl(sreg, e1, 64);
            int s2 = __shfl(sreg, e2, 64), s3 = __shfl(sreg, e3, 64);
            unsigned int v0 = h2u[(size_t)s0 * 32 + m];
            unsigned int v1 = h2u[(size_t)s1 * 32 + m];
            unsigned int v2 = h2u[(size_t)s2 * 32 + m];
            unsigned int v3 = h2u[(size_t)s3 * 32 + m];
            float w0 = __shfl(wr, e0, 64), w1 = __shfl(wr, e1, 64);
            float w2 = __shfl(wr, e2, 64), w3 = __shfl(wr, e3, 64);
            accx += w0 * bfLO(v0); accy += w0 * bfHI(v0);
            accx += w1 * bfLO(v1); accy += w1 * bfHI(v1);
            accx += w2 * bfLO(v2); accy += w2 * bfHI(v2);
            accx += w3 * bfLO(v3); accy += w3 * bfHI(v3);
        }
        for (; e + 2 <= rem; e += 2) {
            int eh = e + half;
            int s = __shfl(sreg, eh, 64);
            float w = __shfl(wr, eh, 64);
            unsigned int v = h2u[(size_t)s * 32 + m];
            accx += w * bfLO(v); accy += w * bfHI(v);
        }
        if (e < rem) {   // odd tail: half 0 only
            int s = __shfl(sreg, e, 64);
            float w = __shfl(wr, e, 64);
            if (half == 0) {
                unsigned int v = h2u[(size_t)s * 32 + m];
                accx += w * bfLO(v); accy += w * bfHI(v);
            }
        }
    }
    // merge halves + den reduce
    accx += __shfl_xor(accx, 32, 64);
    accy += __shfl_xor(accy, 32, 64);
#pragma unroll
    for (int off = 32; off; off >>= 1) den += __shfl_xor(den, off, 64);
    if (half == 0) {
        float inv = 1.0f / (den + 1e-16f);
        float v0 = fmaxf(accx * inv + b2[2 * m], 0.f);
        float v1 = fmaxf(accy * inv + b2[2 * m + 1], 0.f);
        const int rep = blockIdx.x & (N_REP - 1);
        float* sb = sums + (size_t)rep * (N_GRAPHS * 64) + batch[d] * 64;
        atomicAdd(&sb[2 * m], v0);
        atomicAdd(&sb[2 * m + 1], v1);
    }
}

// ---------------- Final: reduce replicas + mean + 64->2 linear ----------------
__global__ __launch_bounds__(64) void k_final(const float* __restrict__ sums,
                                              const int* __restrict__ batch,
                                              const float* __restrict__ linW,
                                              const float* __restrict__ linb,
                                              float* __restrict__ out) {
    const int g = blockIdx.x;
    const int lane = threadIdx.x;
    float s = 0.f;
#pragma unroll 8
    for (int r = 0; r < N_REP; ++r)
        s += sums[(size_t)r * (N_GRAPHS * 64) + g * 64 + lane];
    int beg = lower_bound_i(batch, N_NODES, g);
    int end = lower_bound_i(batch, N_NODES, g + 1);
    float val = s / fmaxf((float)(end - beg), 1.0f);
    float v0 = val * linW[lane * 2 + 0];
    float v1 = val * linW[lane * 2 + 1];
#pragma unroll
    for (int off = 32; off; off >>= 1) {
        v0 += __shfl_xor(v0, off, 64);
        v1 += __shfl_xor(v1, off, 64);
    }
    if (lane == 0) {
        out[g * 2 + 0] = v0 + linb[0];
        out[g * 2 + 1] = v1 + linb[1];
    }
}

extern "C" void kernel_launch(void* const* d_in, const int* in_sizes, int n_in,
                              void* d_out, int out_size, void* d_ws, size_t ws_size,
                              hipStream_t stream) {
    const float* x    = (const float*)d_in[0];
    const int*   ei   = (const int*)d_in[1];
    const int*   bat  = (const int*)d_in[2];
    const float* W1   = (const float*)d_in[3];
    const float* as1  = (const float*)d_in[4];
    const float* ad1  = (const float*)d_in[5];
    const float* b1   = (const float*)d_in[6];
    const float* W2   = (const float*)d_in[7];
    const float* as2  = (const float*)d_in[8];
    const float* ad2  = (const float*)d_in[9];
    const float* b2   = (const float*)d_in[10];
    const float* linW = (const float*)d_in[11];
    const float* linb = (const float*)d_in[12];
    float* out = (float*)d_out;

    const int* src = ei;
    const int* dst = ei + N_EDGES;

    char* w = (char*)d_ws;
    unsigned short* out1rm = (unsigned short*)w; w += (size_t)N_NODES * 256 * 2;
    float4* a_s1 = (float4*)w; w += (size_t)N_NODES * 16;
    float4* a_d1 = (float4*)w; w += (size_t)N_NODES * 16;
    unsigned short* h2b = (unsigned short*)w; w += (size_t)N_NODES * 64 * 2;
    float* a_s2  = (float*)w; w += (size_t)N_NODES * 4;
    float* a_d2  = (float*)w; w += (size_t)N_NODES * 4;
    // counts + sums adjacent: ONE k_zero covers both
    int* counts  = (int*)w;   w += (size_t)N_NODES * 4;
    float* sums  = (float*)w; w += (size_t)N_REP * N_GRAPHS * 64 * 4;
    int* row_start = (int*)w; w += (size_t)(N_NODES + 64) * 4;
    int* lpref     = (int*)w; w += (size_t)N_NODES * 4;
    int* rank      = (int*)w; w += (size_t)N_EDGES * 4;
    int* csr_src   = (int*)w; w += (size_t)N_EDGES * 4;
    int* blk_sum   = (int*)w; w += 128 * 4;
    int* blk_base  = (int*)w; w += 128 * 4;

    // CSR build: atomic rank pass -> scan -> atomic-free scatter
    k_zero<<<(ZERO_INT4 + 255) / 256, 256, 0, stream>>>((int4*)counts);
    k_countrank<<<(N_EDGES / 4 + 255) / 256, 256, 0, stream>>>(dst, counts, rank);
    k_scan1<<<SCAN_NB, SCAN_BS, 0, stream>>>(counts, lpref, blk_sum);
    k_scan2<<<1, 128, 0, stream>>>(blk_sum, blk_base, row_start);
    k_scan3<<<SCAN_NB, SCAN_BS, 0, stream>>>(lpref, blk_base, row_start);
    k_scatter<<<(N_EDGES / 4 + 255) / 256, 256, 0, stream>>>(src, dst, rank, row_start, csr_src);

    // Layer 1
    k_gemm1<<<(N_NODES + 3) / 4, 256, 0, stream>>>(x, W1, as1, ad1, a_s1, a_d1);
    k_agg1<<<N_NODES / 16, 256, 0, stream>>>(x, W1, a_s1, a_d1, row_start, csr_src, b1, out1rm);
    // Layer 2 (MFMA)
    k_gemm2<<<(N_NODES + 63) / 64, 256, 0, stream>>>(out1rm, W2, as2, ad2, h2b, a_s2, a_d2);
    k_agg2<<<(N_NODES + 3) / 4, 256, 0, stream>>>(h2b, a_s2, a_d2, row_start, csr_src, b2,
                                                  bat, sums);
    // Reduce replicas + mean + linear
    k_final<<<N_GRAPHS, 64, 0, stream>>>(sums, bat, linW, linb, out);
}

// Round 16
// 205.819 us; speedup vs baseline: 1.3264x; 1.0109x over previous
//
#include <hip/hip_runtime.h>
#include <math.h>

#define N_NODES 50000
#define N_EDGES 800000
#define N_GRAPHS 64
#define NEG_SLOPE 0.2f
#define SCAN_BS 512
#define SCAN_NB ((N_NODES + SCAN_BS - 1) / SCAN_BS)   // 98
#define N_REP 64   // pooled-sum replicas (contention breaker)
#define ZERO_INT4 ((N_NODES * 4 + N_REP * N_GRAPHS * 64 * 4) / 16)
#define SCAT_GRID 2048
#define NPX (N_NODES / 8)   // 6250 nodes per xcd-range

typedef __attribute__((ext_vector_type(8))) short short8;
typedef __attribute__((ext_vector_type(4))) float f32x4;

__device__ __forceinline__ float lrelu(float x) { return x > 0.f ? x : NEG_SLOPE * x; }

__device__ __forceinline__ unsigned short f2bf(float f) {
    union { float f; unsigned int u; } v; v.f = f;
    unsigned int r = (v.u + 0x7fffu + ((v.u >> 16) & 1u)) >> 16;  // RNE
    return (unsigned short)r;
}
__device__ __forceinline__ float bf2f(unsigned short b) {
    union { unsigned int u; float f; } v; v.u = ((unsigned int)b) << 16;
    return v.f;
}
__device__ __forceinline__ float bfLO(unsigned int u) {
    union { unsigned int u; float f; } v; v.u = u << 16;
    return v.f;
}
__device__ __forceinline__ float bfHI(unsigned int u) {
    union { unsigned int u; float f; } v; v.u = u & 0xffff0000u;
    return v.f;
}

__device__ __forceinline__ int lower_bound_i(const int* __restrict__ a, int n, int v) {
    int lo = 0, hi = n;
    while (lo < hi) { int m = (lo + hi) >> 1; if (a[m] < v) lo = m + 1; else hi = m; }
    return lo;
}

// ---------------- zero counts+sums ----------------
__global__ void k_zero(int4* __restrict__ p) {
    int i = blockIdx.x * blockDim.x + threadIdx.x;
    if (i < ZERO_INT4) p[i] = make_int4(0, 0, 0, 0);
}

// ---------------- CSR build: count + per-edge rank (atomic pass) ----------------
__global__ void k_countrank(const int* __restrict__ dst, int* __restrict__ cnt,
                            int* __restrict__ rank) {
    const int base = (blockIdx.x * blockDim.x + threadIdx.x) * 4;
    if (base + 4 <= N_EDGES) {
        int4 d4 = *(const int4*)(dst + base);
        int4 r;
        r.x = atomicAdd(&cnt[d4.x], 1);
        r.y = atomicAdd(&cnt[d4.y], 1);
        r.z = atomicAdd(&cnt[d4.z], 1);
        r.w = atomicAdd(&cnt[d4.w], 1);
        *(int4*)(rank + base) = r;
    } else {
        for (int e = base; e < N_EDGES; ++e) rank[e] = atomicAdd(&cnt[dst[e]], 1);
    }
}

// ---------------- CSR build: XCD-tiled atomic-free scatter ----------------
// blocks with blockIdx&7==r write only dst-range [r*NPX,(r+1)*NPX): the CSR
// window (~400KB) stays resident in that XCD's L2 so scattered 4B stores merge.
__global__ __launch_bounds__(256) void k_scatter(const int* __restrict__ src,
                                                 const int* __restrict__ dst,
                                                 const int* __restrict__ rank,
                                                 const int* __restrict__ row_start,
                                                 int* __restrict__ csr_src) {
    const int r = blockIdx.x & 7;
    const int slice = blockIdx.x >> 3;                  // 0..255
    const int lo = r * NPX;
    const int per = (N_EDGES + (SCAT_GRID / 8) - 1) / (SCAT_GRID / 8);  // 3125
    const int e0 = slice * per;
    const int e1 = min(e0 + per, N_EDGES);
    for (int e = e0 + threadIdx.x; e < e1; e += 256) {
        int d = dst[e];
        if ((unsigned)(d - lo) < (unsigned)NPX) {
            csr_src[row_start[d] + rank[e]] = src[e];
        }
    }
}

__global__ __launch_bounds__(SCAN_BS) void k_scan1(const int* __restrict__ cnt,
                                                   int* __restrict__ local_pref,
                                                   int* __restrict__ blk_sum) {
    const int t = threadIdx.x;
    const int gid = blockIdx.x * SCAN_BS + t;
    const int lane = t & 63, w = t >> 6;
    int v = (gid < N_NODES) ? cnt[gid] : 0;
    int x = v;
#pragma unroll
    for (int off = 1; off < 64; off <<= 1) {
        int y = __shfl_up(x, off, 64);
        if (lane >= off) x += y;
    }
    __shared__ int wsum[SCAN_BS / 64];
    __shared__ int wpre[SCAN_BS / 64];
    if (lane == 63) wsum[w] = x;
    __syncthreads();
    if (t == 0) {
        int run = 0;
#pragma unroll
        for (int i = 0; i < SCAN_BS / 64; ++i) { wpre[i] = run; run += wsum[i]; }
    }
    __syncthreads();
    int excl = x - v + wpre[w];
    if (gid < N_NODES) local_pref[gid] = excl;
    if (t == SCAN_BS - 1) blk_sum[blockIdx.x] = excl + v;
}

__global__ __launch_bounds__(128) void k_scan2(const int* __restrict__ blk_sum,
                                               int* __restrict__ blk_base,
                                               int* __restrict__ row_start) {
    const int t = threadIdx.x;
    const int lane = t & 63;
    int v = (t < SCAN_NB) ? blk_sum[t] : 0;
    int x = v;
#pragma unroll
    for (int off = 1; off < 64; off <<= 1) {
        int y = __shfl_up(x, off, 64);
        if (lane >= off) x += y;
    }
    __shared__ int wsum0;
    if (t == 63) wsum0 = x;
    __syncthreads();
    int excl = x - v + ((t >= 64) ? wsum0 : 0);
    if (t < SCAN_NB) blk_base[t] = excl;
    if (t == 127) row_start[N_NODES] = excl + v;  // grand total
}

__global__ __launch_bounds__(SCAN_BS) void k_scan3(const int* __restrict__ local_pref,
                                                   const int* __restrict__ blk_base,
                                                   int* __restrict__ row_start) {
    const int gid = blockIdx.x * SCAN_BS + threadIdx.x;
    if (gid < N_NODES) row_start[gid] = local_pref[gid] + blk_base[blockIdx.x];
}

// ---------------- Layer 1 logits: a_s/a_d per node (h1 NOT materialized) -----
__global__ __launch_bounds__(256) void k_gemm1(const float* __restrict__ x,
                                               const float* __restrict__ W1,
                                               const float* __restrict__ att_s,
                                               const float* __restrict__ att_d,
                                               float4* __restrict__ a_s,
                                               float4* __restrict__ a_d) {
    __shared__ float Ws[5 * 256];
    const int t = threadIdx.x;
    for (int i = t; i < 5 * 256; i += 256) Ws[i] = W1[i];
    __syncthreads();
    const int wave = t >> 6, lane = t & 63;
    const int n = blockIdx.x * 4 + wave;
    if (n >= N_NODES) return;
    float x0 = x[n * 5 + 0], x1 = x[n * 5 + 1], x2 = x[n * 5 + 2],
          x3 = x[n * 5 + 3], x4 = x[n * 5 + 4];
    float vs[4], vd[4];
#pragma unroll
    for (int hd = 0; hd < 4; ++hd) {
        const int c = hd * 64 + lane;
        float h = x0 * Ws[c] + x1 * Ws[256 + c] + x2 * Ws[512 + c] +
                  x3 * Ws[768 + c] + x4 * Ws[1024 + c];
        vs[hd] = h * att_s[c];
        vd[hd] = h * att_d[c];
    }
#pragma unroll
    for (int off = 32; off; off >>= 1) {
#pragma unroll
        for (int hd = 0; hd < 4; ++hd) {
            vs[hd] += __shfl_xor(vs[hd], off, 64);
            vd[hd] += __shfl_xor(vd[hd], off, 64);
        }
    }
    if (lane == 0) {
        a_s[n] = make_float4(vs[0], vs[1], vs[2], vs[3]);
        a_d[n] = make_float4(vd[0], vd[1], vd[2], vd[3]);
    }
}

// ---------------- Layer 1 aggregation: SUM-SWAPPED ----------------
__global__ __launch_bounds__(256) void k_agg1(const float* __restrict__ x,
                                              const float* __restrict__ W1,
                                              const float4* __restrict__ asv,
                                              const float4* __restrict__ adv,
                                              const int* __restrict__ row_start,
                                              const int* __restrict__ csr_src,
                                              const float* __restrict__ b1,
                                              unsigned short* __restrict__ out1rm) {
    __shared__ float hand[4][4][24];   // [wave][grp][4 den + 20 Xw]
    const int t = threadIdx.x;
    const int wave = t >> 6, lane = t & 63;
    const int grp = lane >> 4, l16 = lane & 15;
    const int d = blockIdx.x * 16 + wave * 4 + grp;   // exact cover

    float w1r[4][5], bias[4];
#pragma unroll
    for (int h = 0; h < 4; ++h) {
#pragma unroll
        for (int i = 0; i < 5; ++i) w1r[h][i] = W1[i * 256 + h * 64 + lane];
        bias[h] = b1[h * 64 + lane];
    }

    const int beg = row_start[d], end = row_start[d + 1];
    const float4 ad = adv[d];

    float den[4] = {0.f, 0.f, 0.f, 0.f};
    float xw[4][5];
#pragma unroll
    for (int h = 0; h < 4; ++h)
#pragma unroll
        for (int i = 0; i < 5; ++i) xw[h][i] = 0.f;

    for (int cb = beg; cb < end; cb += 16) {
        const int j = cb + l16;
        if (j < end) {
            const int s = csr_src[j];
            const float4 a = asv[s];
            float w[4];
            w[0] = __expf(lrelu(a.x + ad.x));
            w[1] = __expf(lrelu(a.y + ad.y));
            w[2] = __expf(lrelu(a.z + ad.z));
            w[3] = __expf(lrelu(a.w + ad.w));
            const float* xp = x + (size_t)s * 5;
            float xv[5];
#pragma unroll
            for (int i = 0; i < 5; ++i) xv[i] = xp[i];
#pragma unroll
            for (int h = 0; h < 4; ++h) {
                den[h] += w[h];
#pragma unroll
                for (int i = 0; i < 5; ++i) xw[h][i] += w[h] * xv[i];
            }
        }
    }

#pragma unroll
    for (int off = 1; off < 16; off <<= 1) {
#pragma unroll
        for (int h = 0; h < 4; ++h) {
            den[h] += __shfl_xor(den[h], off, 64);
#pragma unroll
            for (int i = 0; i < 5; ++i) xw[h][i] += __shfl_xor(xw[h][i], off, 64);
        }
    }

    {   // self loop
        const float4 as = asv[d];
        float w[4];
        w[0] = __expf(lrelu(as.x + ad.x));
        w[1] = __expf(lrelu(as.y + ad.y));
        w[2] = __expf(lrelu(as.z + ad.z));
        w[3] = __expf(lrelu(as.w + ad.w));
        const float* xp = x + (size_t)d * 5;
        float xv[5];
#pragma unroll
        for (int i = 0; i < 5; ++i) xv[i] = xp[i];
#pragma unroll
        for (int h = 0; h < 4; ++h) {
            den[h] += w[h];
#pragma unroll
            for (int i = 0; i < 5; ++i) xw[h][i] += w[h] * xv[i];
        }
    }

    if (l16 == 0) {
#pragma unroll
        for (int h = 0; h < 4; ++h) hand[wave][grp][h] = den[h];
#pragma unroll
        for (int h = 0; h < 4; ++h)
#pragma unroll
            for (int i = 0; i < 5; ++i) hand[wave][grp][4 + h * 5 + i] = xw[h][i];
    }
    __syncthreads();

#pragma unroll
    for (int n = 0; n < 4; ++n) {
        const int dn = blockIdx.x * 16 + wave * 4 + n;
        unsigned short* op = out1rm + (size_t)dn * 256;
#pragma unroll
        for (int h = 0; h < 4; ++h) {
            const float dh = hand[wave][n][h] + 1e-16f;
            float hh = hand[wave][n][4 + h * 5 + 0] * w1r[h][0]
                     + hand[wave][n][4 + h * 5 + 1] * w1r[h][1]
                     + hand[wave][n][4 + h * 5 + 2] * w1r[h][2]
                     + hand[wave][n][4 + h * 5 + 3] * w1r[h][3]
                     + hand[wave][n][4 + h * 5 + 4] * w1r[h][4];
            op[h * 64 + lane] = f2bf(fmaxf(hh / dh + bias[h], 0.f));
        }
    }
}

// ---------------- Layer 2: MFMA GEMM (50000x256 @ 256x64) + attention logits ----
__global__ __launch_bounds__(256) void k_gemm2(const unsigned short* __restrict__ in,
                                               const float* __restrict__ W2,
                                               const float* __restrict__ att_s2,
                                               const float* __restrict__ att_d2,
                                               unsigned short* __restrict__ h2b,
                                               float* __restrict__ a_s2,
                                               float* __restrict__ a_d2) {
    __shared__ unsigned short lW[16384];  // 32 KB: [s][g][t][c16][j]
    const int t = threadIdx.x;
    for (int idx = t; idx < 16384; idx += 256) {
        int j = idx & 7, c16 = (idx >> 3) & 15, tt = (idx >> 7) & 3,
            g = (idx >> 9) & 3, s = idx >> 11;
        int k = 32 * s + 8 * g + j, c = 16 * tt + c16;
        lW[idx] = f2bf(W2[k * 64 + c]);
    }
    __syncthreads();
    const int wave = t >> 6, lane = t & 63;
    const int g = lane >> 4, c16 = lane & 15;
    const int nb = blockIdx.x * 64 + wave * 16;
    if (nb >= N_NODES) return;

    f32x4 acc[4];
#pragma unroll
    for (int i = 0; i < 4; ++i) acc[i] = (f32x4){0.f, 0.f, 0.f, 0.f};

    const unsigned short* arow = in + (size_t)(nb + c16) * 256;  // A row = lane&15
#pragma unroll
    for (int s = 0; s < 8; ++s) {
        short8 a = *reinterpret_cast<const short8*>(arow + 32 * s + 8 * g);
#pragma unroll
        for (int tt = 0; tt < 4; ++tt) {
            short8 b = *reinterpret_cast<const short8*>(
                lW + ((((s * 4 + g) * 4 + tt) * 16 + c16) << 3));
            acc[tt] = __builtin_amdgcn_mfma_f32_16x16x32_bf16(a, b, acc[tt], 0, 0, 0);
        }
    }

    float attS[4], attD[4];
#pragma unroll
    for (int tt = 0; tt < 4; ++tt) {
        attS[tt] = att_s2[16 * tt + c16];
        attD[tt] = att_d2[16 * tt + c16];
    }
#pragma unroll
    for (int r = 0; r < 4; ++r) {
        const int node = nb + g * 4 + r;
        const bool ok = node < N_NODES;
        float vs = 0.f, vd = 0.f;
#pragma unroll
        for (int tt = 0; tt < 4; ++tt) {
            float v = acc[tt][r];
            if (ok) h2b[(size_t)node * 64 + 16 * tt + c16] = f2bf(v);
            vs += v * attS[tt];
            vd += v * attD[tt];
        }
#pragma unroll
        for (int off = 1; off < 16; off <<= 1) {
            vs += __shfl_xor(vs, off, 64);
            vd += __shfl_xor(vd, off, 64);
        }
        if (ok && c16 == 0) { a_s2[node] = vs; a_d2[node] = vd; }
    }
}

// ---------------- Layer 2 aggregation + fused pool (v4) ----------------
// 2 nodes per wave, 32 lanes/node (lane = uint channel). Edge (src,w) staged in
// LDS once per 32-edge batch; gather loop uses broadcast ds_read, 4-deep ILP.
__global__ __launch_bounds__(256) void k_agg2(const unsigned int* __restrict__ h2u,
                                              const float* __restrict__ as_,
                                              const float* __restrict__ ad_,
                                              const int* __restrict__ row_start,
                                              const int* __restrict__ csr_src,
                                              const float* __restrict__ b2,
                                              const int* __restrict__ batch,
                                              float* __restrict__ sums) {
    __shared__ int2 ew[4][2][32];
    const int t = threadIdx.x;
    const int wid = t >> 6, lane = t & 63;
    const int g = lane >> 5, m = lane & 31;
    const int d = blockIdx.x * 8 + wid * 2 + g;   // exact cover (50000/8=6250)
    const int beg = row_start[d], end = row_start[d + 1];
    const float adl = ad_[d];

    float den = 0.f, accx = 0.f, accy = 0.f;
    for (int c = beg; c < end; c += 32) {
        int rem = end - c; if (rem > 32) rem = 32;
        if (m < rem) {
            int s = csr_src[c + m];
            float w = __expf(lrelu(as_[s] + adl));
            den += w;
            ew[wid][g][m] = make_int2(s, __float_as_int(w));
        }
        int e = 0;
        for (; e + 4 <= rem; e += 4) {
            int2 p0 = ew[wid][g][e],     p1 = ew[wid][g][e + 1];
            int2 p2 = ew[wid][g][e + 2], p3 = ew[wid][g][e + 3];
            unsigned int v0 = h2u[(size_t)p0.x * 32 + m];
            unsigned int v1 = h2u[(size_t)p1.x * 32 + m];
            unsigned int v2 = h2u[(size_t)p2.x * 32 + m];
            unsigned int v3 = h2u[(size_t)p3.x * 32 + m];
            float w0 = __int_as_float(p0.y), w1 = __int_as_float(p1.y);
            float w2 = __int_as_float(p2.y), w3 = __int_as_float(p3.y);
            accx += w0 * bfLO(v0); accy += w0 * bfHI(v0);
            accx += w1 * bfLO(v1); accy += w1 * bfHI(v1);
            accx += w2 * bfLO(v2); accy += w2 * bfHI(v2);
            accx += w3 * bfLO(v3); accy += w3 * bfHI(v3);
        }
        for (; e < rem; ++e) {
            int2 p = ew[wid][g][e];
            unsigned int v = h2u[(size_t)p.x * 32 + m];
            float w = __int_as_float(p.y);
            accx += w * bfLO(v); accy += w * bfHI(v);
        }
    }
#pragma unroll
    for (int off = 16; off; off >>= 1) den += __shfl_xor(den, off, 64);  // in-group
    {   // self loop (uniform per group)
        float w = __expf(lrelu(as_[d] + adl));
        den += w;
        unsigned int v = h2u[(size_t)d * 32 + m];
        accx += w * bfLO(v); accy += w * bfHI(v);
    }
    float inv = 1.0f / (den + 1e-16f);
    float v0 = fmaxf(accx * inv + b2[2 * m], 0.f);
    float v1 = fmaxf(accy * inv + b2[2 * m + 1], 0.f);
    const int rep = ((blockIdx.x << 3) + (wid << 1) + g) & (N_REP - 1);
    float* sb = sums + (size_t)rep * (N_GRAPHS * 64) + batch[d] * 64;
    atomicAdd(&sb[2 * m], v0);
    atomicAdd(&sb[2 * m + 1], v1);
}

// ---------------- Final: reduce replicas + mean + 64->2 linear ----------------
__global__ __launch_bounds__(64) void k_final(const float* __restrict__ sums,
                                              const int* __restrict__ batch,
                                              const float* __restrict__ linW,
                                              const float* __restrict__ linb,
                                              float* __restrict__ out) {
    const int g = blockIdx.x;
    const int lane = threadIdx.x;
    float s = 0.f;
#pragma unroll 8
    for (int r = 0; r < N_REP; ++r)
        s += sums[(size_t)r * (N_GRAPHS * 64) + g * 64 + lane];
    int beg = lower_bound_i(batch, N_NODES, g);
    int end = lower_bound_i(batch, N_NODES, g + 1);
    float val = s / fmaxf((float)(end - beg), 1.0f);
    float v0 = val * linW[lane * 2 + 0];
    float v1 = val * linW[lane * 2 + 1];
#pragma unroll
    for (int off = 32; off; off >>= 1) {
        v0 += __shfl_xor(v0, off, 64);
        v1 += __shfl_xor(v1, off, 64);
    }
    if (lane == 0) {
        out[g * 2 + 0] = v0 + linb[0];
        out[g * 2 + 1] = v1 + linb[1];
    }
}

extern "C" void kernel_launch(void* const* d_in, const int* in_sizes, int n_in,
                              void* d_out, int out_size, void* d_ws, size_t ws_size,
                              hipStream_t stream) {
    const float* x    = (const float*)d_in[0];
    const int*   ei   = (const int*)d_in[1];
    const int*   bat  = (const int*)d_in[2];
    const float* W1   = (const float*)d_in[3];
    const float* as1  = (const float*)d_in[4];
    const float* ad1  = (const float*)d_in[5];
    const float* b1   = (const float*)d_in[6];
    const float* W2   = (const float*)d_in[7];
    const float* as2  = (const float*)d_in[8];
    const float* ad2  = (const float*)d_in[9];
    const float* b2   = (const float*)d_in[10];
    const float* linW = (const float*)d_in[11];
    const float* linb = (const float*)d_in[12];
    float* out = (float*)d_out;

    const int* src = ei;
    const int* dst = ei + N_EDGES;

    char* w = (char*)d_ws;
    unsigned short* out1rm = (unsigned short*)w; w += (size_t)N_NODES * 256 * 2;
    float4* a_s1 = (float4*)w; w += (size_t)N_NODES * 16;
    float4* a_d1 = (float4*)w; w += (size_t)N_NODES * 16;
    unsigned short* h2b = (unsigned short*)w; w += (size_t)N_NODES * 64 * 2;
    float* a_s2  = (float*)w; w += (size_t)N_NODES * 4;
    float* a_d2  = (float*)w; w += (size_t)N_NODES * 4;
    // counts + sums adjacent: ONE k_zero covers both
    int* counts  = (int*)w;   w += (size_t)N_NODES * 4;
    float* sums  = (float*)w; w += (size_t)N_REP * N_GRAPHS * 64 * 4;
    int* row_start = (int*)w; w += (size_t)(N_NODES + 64) * 4;
    int* lpref     = (int*)w; w += (size_t)N_NODES * 4;
    int* rank      = (int*)w; w += (size_t)N_EDGES * 4;
    int* csr_src   = (int*)w; w += (size_t)N_EDGES * 4;
    int* blk_sum   = (int*)w; w += 128 * 4;
    int* blk_base  = (int*)w; w += 128 * 4;

    // CSR build: atomic rank pass -> scan -> XCD-tiled atomic-free scatter
    k_zero<<<(ZERO_INT4 + 255) / 256, 256, 0, stream>>>((int4*)counts);
    k_countrank<<<(N_EDGES / 4 + 255) / 256, 256, 0, stream>>>(dst, counts, rank);
    k_scan1<<<SCAN_NB, SCAN_BS, 0, stream>>>(counts, lpref, blk_sum);
    k_scan2<<<1, 128, 0, stream>>>(blk_sum, blk_base, row_start);
    k_scan3<<<SCAN_NB, SCAN_BS, 0, stream>>>(lpref, blk_base, row_start);
    k_scatter<<<SCAT_GRID, 256, 0, stream>>>(src, dst, rank, row_start, csr_src);

    // Layer 1
    k_gemm1<<<(N_NODES + 3) / 4, 256, 0, stream>>>(x, W1, as1, ad1, a_s1, a_d1);
    k_agg1<<<N_NODES / 16, 256, 0, stream>>>(x, W1, a_s1, a_d1, row_start, csr_src, b1, out1rm);
    // Layer 2 (MFMA)
    k_gemm2<<<(N_NODES + 63) / 64, 256, 0, stream>>>(out1rm, W2, as2, ad2, h2b, a_s2, a_d2);
    k_agg2<<<N_NODES / 8, 256, 0, stream>>>((const unsigned int*)h2b, a_s2, a_d2,
                                            row_start, csr_src, b2, bat, sums);
    // Reduce replicas + mean + linear
    k_final<<<N_GRAPHS, 64, 0, stream>>>(sums, bat, linW, linb, out);
}